// Round 1
// 99.415 us; speedup vs baseline: 1.0252x; 1.0252x over previous
//
#include <hip/hip_runtime.h>

// DTW loss: sum |preds[b, path_i[b,p]] - targets[b, path_j[b,p]]|_1 / (B*S)
// B=256, S=8192, P=16383. preds/targets fp32 (B,S,2); path_* int32 (B,P).
//
// R7: split-phase overlap. Previous structure staged everything, drained
// vmcnt(0) at one __syncthreads, then ran BOTH LDS gathers fully exposed
// (~1.5-1.7 us with HBM idle). New structure: ordered vm issue
// [predsDMA][pi][targetsDMA][pj], then s_waitcnt vmcnt(20) + raw s_barrier
// waits only the oldest 20 ops (preds deposits + pi). The preds gather
// (16 ds_read_b64 -> 32 VGPRs) runs while targets/pj still stream from HBM.
// Second wait vmcnt(0) + barrier, then only the targets gather is exposed.
// vmcnt miscount is fail-safe: extra ops only make vmcnt(20) wait MORE.
//
// Floor arithmetic: 66.3 MB @ ~6.3 TB/s = 10.5 us stream + ~0.85 us exposed
// targets gather + drain/reduce ~0.5 + final kernel/gaps ~1.5.

#define BB 256
#define SS 8192
#define PP 16383
#define NT 1024
#define NIT 16           // ceil(PP / NT): 15 full iters + 1 guarded

__global__ __launch_bounds__(NT, 4) void dtw_loss_kernel(
    const float* __restrict__ preds,
    const float* __restrict__ targets,
    const int* __restrict__ path_i,
    const int* __restrict__ path_j,
    float* __restrict__ partial)   // 256 slots, one per block; no init needed
{
    // 128 KB: preds window fp32 float2 in [0, 2*SS) floats, targets after.
    __shared__ float lds[4 * SS];
    __shared__ float wred[16];

    const int tid   = threadIdx.x;
    const int batch = blockIdx.x;          // one block per batch
    const int wave  = tid >> 6;            // 0..15
    const int lane  = tid & 63;

    const char* pbase = (const char*)(preds   + (size_t)batch * SS * 2);  // 64 KB
    const char* tbase = (const char*)(targets + (size_t)batch * SS * 2);  // 64 KB
    const int* __restrict__ pi = path_i + (size_t)batch * PP;
    const int* __restrict__ pj = path_j + (size_t)batch * PP;

    // --- Group A: preds window via global->LDS DMA (4 x 1 KB per wave) ---
    #pragma unroll
    for (int u = 0; u < 4; ++u) {
        const int off = (wave * 4 + u) * 1024;          // byte offset in window
        __builtin_amdgcn_global_load_lds(
            (const __attribute__((address_space(1))) void*)(pbase + off + lane * 16),
            (__attribute__((address_space(3))) void*)((char*)lds + off),
            16, 0, 0);
    }
    __builtin_amdgcn_sched_barrier(0);

    // --- Group B: pi index loads (16 dwords / thread) ---
    unsigned ii[NIT];
    #pragma unroll
    for (int u = 0; u < NIT; ++u) {
        int k = u * NT + tid;
        if (u == NIT - 1) k = min(k, PP - 1);
        ii[u] = (unsigned)pi[k];
    }
    __builtin_amdgcn_sched_barrier(0);

    // --- Group C: targets window DMA ---
    #pragma unroll
    for (int u = 0; u < 4; ++u) {
        const int off = (wave * 4 + u) * 1024;
        __builtin_amdgcn_global_load_lds(
            (const __attribute__((address_space(1))) void*)(tbase + off + lane * 16),
            (__attribute__((address_space(3))) void*)((char*)lds + 65536 + off),
            16, 0, 0);
    }
    __builtin_amdgcn_sched_barrier(0);

    // --- Group D: pj index loads ---
    unsigned jj[NIT];
    #pragma unroll
    for (int u = 0; u < NIT; ++u) {
        int k = u * NT + tid;
        if (u == NIT - 1) k = min(k, PP - 1);
        jj[u] = (unsigned)pj[k];
    }
    __builtin_amdgcn_sched_barrier(0);

    // Pin ii AFTER all 40 vm-ops issued: compiler emits the wait for the pi
    // loads only (C+D are younger), so this does not drain targets/pj.
    #pragma unroll
    for (int u = 0; u < NIT; ++u)
        asm volatile("" : "+v"(ii[u]));
    // W1: this wave's preds deposits + pi complete (oldest 20 of 40 ops);
    // barrier aligns all waves -> full preds window visible in LDS.
    asm volatile("s_waitcnt vmcnt(20)" ::: "memory");
    __builtin_amdgcn_s_barrier();
    __builtin_amdgcn_sched_barrier(0);

    // --- Phase B: gather preds values while targets/pj still stream ---
    const float2* __restrict__ lp = (const float2*)lds;            // preds
    const float2* __restrict__ lt = (const float2*)(lds + 2 * SS); // targets
    float ax[NIT], ay[NIT];
    #pragma unroll
    for (int u = 0; u < NIT; ++u) {
        const float2 a = lp[ii[u]];
        ax[u] = a.x; ay[u] = a.y;
    }
    #pragma unroll
    for (int u = 0; u < NIT; ++u)
        asm volatile("" : "+v"(ax[u]), "+v"(ay[u]));   // lgkmcnt drain (hidden)
    __builtin_amdgcn_sched_barrier(0);

    // Pin jj (compiler waits only targets-younger ops), then full drain:
    // all targets deposits done -> barrier 2.
    #pragma unroll
    for (int u = 0; u < NIT; ++u)
        asm volatile("" : "+v"(jj[u]));
    asm volatile("s_waitcnt vmcnt(0)" ::: "memory");
    __builtin_amdgcn_s_barrier();
    __builtin_amdgcn_sched_barrier(0);

    // --- Phase C: gather targets, compute, reduce ---
    float acc = 0.0f;
    #pragma unroll
    for (int u = 0; u < NIT; ++u) {
        const float2 b = lt[jj[u]];
        const float d = fabsf(ax[u] - b.x) + fabsf(ay[u] - b.y);
        if (u < NIT - 1 || u * NT + tid < PP) acc += d;   // tail: 1023 valid
    }

    // --- wave reduce -> block reduce -> ONE plain store per block ---
    #pragma unroll
    for (int off = 32; off > 0; off >>= 1)
        acc += __shfl_down(acc, off, 64);
    if (lane == 0) wred[wave] = acc;
    __syncthreads();
    if (tid < 16) {
        float s = wred[tid];
        s += __shfl_down(s, 8, 64);
        s += __shfl_down(s, 4, 64);
        s += __shfl_down(s, 2, 64);
        s += __shfl_down(s, 1, 64);
        if (tid == 0) partial[batch] = s;   // unique slot: no atomic, no init
    }
}

__global__ __launch_bounds__(64) void dtw_final_kernel(
    const float* __restrict__ partial, float* __restrict__ out)
{
    // 256 partials = 64 lanes x float4; kernel boundary guarantees visibility.
    const float4 v = ((const float4*)partial)[threadIdx.x];
    float s = (v.x + v.y) + (v.z + v.w);
    #pragma unroll
    for (int off = 32; off > 0; off >>= 1)
        s += __shfl_down(s, off, 64);
    if (threadIdx.x == 0)
        out[0] = s * (1.0f / ((float)BB * (float)SS));   // *2^-21, exact scale
}

extern "C" void kernel_launch(void* const* d_in, const int* in_sizes, int n_in,
                              void* d_out, int out_size, void* d_ws, size_t ws_size,
                              hipStream_t stream) {
    const float* preds   = (const float*)d_in[0];
    const float* targets = (const float*)d_in[1];
    const int*   path_i  = (const int*)d_in[2];
    const int*   path_j  = (const int*)d_in[3];
    float* partial = (float*)d_ws;    // 256 floats; every slot written each call
    float* out     = (float*)d_out;

    dtw_loss_kernel<<<BB, NT, 0, stream>>>(preds, targets, path_i, path_j, partial);
    dtw_final_kernel<<<1, 64, 0, stream>>>(partial, out);
}